// Round 19
// baseline (63.224 us; speedup 1.0000x reference)
//
#include <hip/hip_runtime.h>

// B=4, C=64, H=64, W=64. Tokens N = C*H = 4096, feature dim D = W = 64.
// q = conv1x1(v1,wq,bq); k,v = conv1x1(v2,...); scores = q@k^T (no scale);
// softmax; out = attn@v. Output fp32, flat (B,C,H,W) == (B,N,D).
//
// R19 = R18 with ONE attn delta: pair-barrier (2 tiles per __syncthreads,
// 4 LDS tile-buffers, 64KB). R14 tested this confounded with MFMA-l (+regs,
// spilled); this is the minimal version on the clean R16 body.
// Conv stays MFMA GEMM (R18); combine stays lw-weighted (R16).

#define Bn 4
#define Cc 64
#define HW 4096
#define Nn 4096
#define Dd 64
#define TS (Bn * Nn * Dd)   // elems per (B,N,D) tensor = 1048576
#define LOG2E 1.44269504088896340736f

typedef _Float16 f16;
typedef _Float16 f16x8 __attribute__((ext_vector_type(8)));
typedef _Float16 f16x4 __attribute__((ext_vector_type(4)));
typedef __fp16 fp16x2 __attribute__((ext_vector_type(2)));
typedef float f32x4 __attribute__((ext_vector_type(4)));

__device__ __forceinline__ int swz(int row, int col) {
    return row * 64 + (col ^ ((row & 7) << 3));
}

// Async global->LDS DMA, 16B per lane. LDS dest = uniform base + lane*16.
__device__ __forceinline__ void gl_lds16(const f16* g, f16* l) {
    __builtin_amdgcn_global_load_lds(
        (const __attribute__((address_space(1))) unsigned int*)g,
        (__attribute__((address_space(3))) unsigned int*)l, 16, 0, 0);
}

// ---------------------------------------------------------------------------
// Kernel 1: 1x1 conv as MFMA GEMM (verified R18). blockIdx.z: 0=Q,1=K,2=V.
__global__ __launch_bounds__(512) void qkv_conv(
    const float* __restrict__ v1, const float* __restrict__ v2,
    const float* __restrict__ wq, const float* __restrict__ bq,
    const float* __restrict__ wk, const float* __restrict__ bk,
    const float* __restrict__ wv, const float* __restrict__ bv,
    f16* __restrict__ Qh, f16* __restrict__ Kh, f16* __restrict__ Vh)
{
    __shared__ __align__(16) f16 wl[64 * 72];   // W[o][c], row stride 72
    __shared__ __align__(16) f16 Xt[64 * 72];   // X^T[dp][c], row stride 72
    __shared__ __align__(16) float bl[64];

    const int t    = threadIdx.x;
    const int lane = t & 63, wvi = t >> 6;
    const int g = lane >> 4, c = lane & 15;
    const int b   = blockIdx.y;
    const int blk = blockIdx.x;
    const int z   = blockIdx.z;          // 0=Q, 1=K, 2=V

    const float* w    = (z == 0) ? wq : (z == 1) ? wk : wv;
    const float* bias = (z == 0) ? bq : (z == 1) ? bk : bv;
    const float* x    = ((z == 0) ? v1 : v2) + (size_t)b * (Cc * HW) + blk * 64;
    f16* dst          = (z == 0) ? Qh : (z == 1) ? Kh : Vh;
    const float scale = (z == 0) ? LOG2E : 1.0f;

    for (int i = t; i < 4096; i += 512)
        wl[(i >> 6) * 72 + (i & 63)] = (f16)(w[i] * scale);
    if (t < 64) bl[t] = bias[t] * scale;
    {
        const int cch = t >> 3, dp0 = (t & 7) * 8;
        float4 x0 = *(const float4*)(x + (size_t)cch * HW + dp0);
        float4 x1 = *(const float4*)(x + (size_t)cch * HW + dp0 + 4);
        Xt[(dp0 + 0) * 72 + cch] = (f16)x0.x;
        Xt[(dp0 + 1) * 72 + cch] = (f16)x0.y;
        Xt[(dp0 + 2) * 72 + cch] = (f16)x0.z;
        Xt[(dp0 + 3) * 72 + cch] = (f16)x0.w;
        Xt[(dp0 + 4) * 72 + cch] = (f16)x1.x;
        Xt[(dp0 + 5) * 72 + cch] = (f16)x1.y;
        Xt[(dp0 + 6) * 72 + cch] = (f16)x1.z;
        Xt[(dp0 + 7) * 72 + cch] = (f16)x1.w;
    }
    __syncthreads();

    const int fn  = wvi & 3;        // dp block
    const int fo2 = (wvi >> 2) * 2; // first of 2 o-blocks

    f16x8 xb0 = *(const f16x8*)(Xt + (fn * 16 + c) * 72 + g * 8);
    f16x8 xb1 = *(const f16x8*)(Xt + (fn * 16 + c) * 72 + 32 + g * 8);

    #pragma unroll
    for (int fi = 0; fi < 2; ++fi) {
        const int fo = fo2 + fi;
        f16x8 wa0 = *(const f16x8*)(wl + (fo * 16 + c) * 72 + g * 8);
        f16x8 wa1 = *(const f16x8*)(wl + (fo * 16 + c) * 72 + 32 + g * 8);
        f32x4 acc = *(const f32x4*)(bl + fo * 16 + g * 4);   // bias init
        acc = __builtin_amdgcn_mfma_f32_16x16x32_f16(wa0, xb0, acc, 0, 0, 0);
        acc = __builtin_amdgcn_mfma_f32_16x16x32_f16(wa1, xb1, acc, 0, 0, 0);
        #pragma unroll
        for (int r = 0; r < 4; ++r) {
            const int o = fo * 16 + g * 4 + r;
            const int n = o * 64 + blk;
            dst[(size_t)b * (Nn * Dd) + (size_t)n * 64 + fn * 16 + c] = (f16)acc[r];
        }
    }
}

// ---------------------------------------------------------------------------
// Kernel 2: transpose V (B,N,D) -> Vt (B,D,N).
__global__ __launch_bounds__(256) void vtrans(const f16* __restrict__ Vh,
                                              f16* __restrict__ Vt)
{
    __shared__ f16 tile[64][72];
    const int t  = threadIdx.x;
    const int n0 = blockIdx.x * 64;
    const int b  = blockIdx.y;
    for (int i = t; i < 4096; i += 256) {
        int r = i >> 6, c = i & 63;
        tile[r][c] = Vh[(size_t)b * (Nn * Dd) + (size_t)(n0 + r) * 64 + c];
    }
    __syncthreads();
    for (int i = t; i < 4096; i += 256) {
        int w = i >> 6, n = i & 63;
        Vt[(size_t)b * (Dd * Nn) + (size_t)w * Nn + n0 + n] = tile[n][w];
    }
}

// ---------------------------------------------------------------------------
// Kernel 3: flash attention, split-K. R16 body, pair-barrier: 2 tiles per
// __syncthreads, 4 LDS tile-buffers (64KB), 4 DMA issues per pair.
// 512 threads = 8 waves x 32 q-rows; grid (16, S, 4); S=8 -> 512 blocks
// = 2 resident blocks/CU at (512,4).
__global__ __launch_bounds__(512, 4) void attn(
    const f16* __restrict__ Qhg, const f16* __restrict__ Khg,
    const f16* __restrict__ Vtg,
    float* __restrict__ out, f16* __restrict__ Opart, float* __restrict__ lw)
{
    __shared__ __align__(16) f16 KT[2][2][4096];  // [buf][sub][key][d] swz
    __shared__ __align__(16) f16 VT[2][2][4096];  // [buf][sub][d][key] swz

    const int t    = threadIdx.x;
    const int lane = t & 63, wvi = t >> 6;      // 8 waves
    const int g = lane >> 4, c = lane & 15;
    const int b  = blockIdx.z;
    const int sp = blockIdx.y;
    const int S  = gridDim.y;
    const int n0 = blockIdx.x * 256;
    const int keysPerSplit = Nn / S;
    const int nPairs = keysPerSplit / 128;      // even tiles for S in {1,2,4,8}
    const int kbase = sp * keysPerSplit;

    const int srow = t >> 3;                      // 0..63
    const int gc   = ((t & 7) ^ (srow & 7)) * 8;  // pre-swizzled global col
    const int ldsoff = (wvi * 8) * 64;            // wave-uniform dest offset

    const f16* Kb = Khg + (size_t)b * (Nn * Dd);
    const f16* Vb = Vtg + (size_t)b * (Dd * Nn);

    f16x8 qbh[2][2];
    #pragma unroll
    for (int qf = 0; qf < 2; ++qf) {
        const int qrow = n0 + wvi * 32 + qf * 16 + c;
        const f16* qhp = Qhg + ((size_t)b * Nn + qrow) * 64;
        #pragma unroll
        for (int ks = 0; ks < 2; ++ks)
            qbh[qf][ks] = *(const f16x8*)(qhp + ks * 32 + g * 8);
    }

    float m_run[2] = {-1e30f, -1e30f}, lpart[2] = {0.f, 0.f};
    f32x4 of[2][4];
    #pragma unroll
    for (int qf = 0; qf < 2; ++qf)
        #pragma unroll
        for (int nf = 0; nf < 4; ++nf)
            #pragma unroll
            for (int r = 0; r < 4; ++r) of[qf][nf][r] = 0.f;

    // Prologue: DMA pair 0 into buffer 0.
    #pragma unroll
    for (int sub = 0; sub < 2; ++sub) {
        const int k0 = kbase + sub * 64;
        gl_lds16(Kb + (size_t)(k0 + srow) * 64 + gc, &KT[0][sub][ldsoff]);
        gl_lds16(Vb + (size_t)srow * Nn + k0 + gc, &VT[0][sub][ldsoff]);
    }
    __syncthreads();
    int cur = 0;

    for (int pr = 0; pr < nPairs; ++pr) {
        if (pr + 1 < nPairs) {
            const int kp = kbase + (pr + 1) * 128;
            #pragma unroll
            for (int sub = 0; sub < 2; ++sub) {
                const int k0 = kp + sub * 64;
                gl_lds16(Kb + (size_t)(k0 + srow) * 64 + gc, &KT[cur ^ 1][sub][ldsoff]);
                gl_lds16(Vb + (size_t)srow * Nn + k0 + gc, &VT[cur ^ 1][sub][ldsoff]);
            }
        }

        #pragma unroll
        for (int sub = 0; sub < 2; ++sub) {
            const f16* KTc = KT[cur][sub];
            const f16* VTc = VT[cur][sub];

            // ---- QK^T (16x16x32; one K-read feeds both qf) ----
            f32x4 accS[2][4];
            #pragma unroll
            for (int qf = 0; qf < 2; ++qf)
                #pragma unroll
                for (int fm = 0; fm < 4; ++fm)
                    #pragma unroll
                    for (int r = 0; r < 4; ++r) accS[qf][fm][r] = 0.f;
            #pragma unroll
            for (int fm = 0; fm < 4; ++fm) {
                const int key = fm * 16 + c;
                f16x8 kh0 = *(const f16x8*)(KTc + swz(key, g * 8));
                f16x8 kh1 = *(const f16x8*)(KTc + swz(key, 32 + g * 8));
                #pragma unroll
                for (int qf = 0; qf < 2; ++qf) {
                    accS[qf][fm] = __builtin_amdgcn_mfma_f32_16x16x32_f16(kh0, qbh[qf][0], accS[qf][fm], 0, 0, 0);
                    accS[qf][fm] = __builtin_amdgcn_mfma_f32_16x16x32_f16(kh1, qbh[qf][1], accS[qf][fm], 0, 0, 0);
                }
            }

            // ---- softmax (defer-max THR=8, log2) + pack P^T B-frags ----
            f16x4 pb[2][4];
            #pragma unroll
            for (int qf = 0; qf < 2; ++qf) {
                float m0 = fmaxf(fmaxf(accS[qf][0][0], accS[qf][0][1]),
                                 fmaxf(accS[qf][0][2], accS[qf][0][3]));
                float m1 = fmaxf(fmaxf(accS[qf][1][0], accS[qf][1][1]),
                                 fmaxf(accS[qf][1][2], accS[qf][1][3]));
                float m2 = fmaxf(fmaxf(accS[qf][2][0], accS[qf][2][1]),
                                 fmaxf(accS[qf][2][2], accS[qf][2][3]));
                float m3 = fmaxf(fmaxf(accS[qf][3][0], accS[qf][3][1]),
                                 fmaxf(accS[qf][3][2], accS[qf][3][3]));
                float tmax = fmaxf(fmaxf(m0, m1), fmaxf(m2, m3));
                tmax = fmaxf(tmax, __shfl_xor(tmax, 16));
                tmax = fmaxf(tmax, __shfl_xor(tmax, 32));
                if (!__all(tmax <= m_run[qf] + 8.f)) {
                    const float mnew = fmaxf(m_run[qf], tmax);
                    const float corr = exp2f(m_run[qf] - mnew);
                    lpart[qf] *= corr;
                    #pragma unroll
                    for (int nf = 0; nf < 4; ++nf)
                        #pragma unroll
                        for (int r = 0; r < 4; ++r) of[qf][nf][r] *= corr;
                    m_run[qf] = mnew;
                }
                float s01 = 0.f, s23 = 0.f;
                #pragma unroll
                for (int fm = 0; fm < 4; ++fm) {
                    #pragma unroll
                    for (int r = 0; r < 4; ++r) {
                        float pp = exp2f(accS[qf][fm][r] - m_run[qf]);  // <= 2^8
                        accS[qf][fm][r] = pp;
                        if (fm < 2) s01 += pp; else s23 += pp;
                    }
                    union { f16x4 v4; fp16x2 h2[2]; } u;
                    u.h2[0] = __builtin_amdgcn_cvt_pkrtz(accS[qf][fm][0], accS[qf][fm][1]);
                    u.h2[1] = __builtin_amdgcn_cvt_pkrtz(accS[qf][fm][2], accS[qf][fm][3]);
                    pb[qf][fm] = u.v4;
                }
                lpart[qf] += s01 + s23;
            }

            // ---- PV (16x16x16): V A-frag read ONCE, feeds both qf ----
            #pragma unroll
            for (int nf = 0; nf < 4; ++nf) {
                #pragma unroll
                for (int fm = 0; fm < 4; ++fm) {
                    f16x4 va = *(const f16x4*)(VTc + swz(nf * 16 + c, fm * 16 + g * 4));
                    of[0][nf] = __builtin_amdgcn_mfma_f32_16x16x16f16(va, pb[0][fm], of[0][nf], 0, 0, 0);
                    of[1][nf] = __builtin_amdgcn_mfma_f32_16x16x16f16(va, pb[1][fm], of[1][nf], 0, 0, 0);
                }
            }
        }

        // ONE barrier per pair: drains DMA (vmcnt) + LDS reads.
        __syncthreads();
        cur ^= 1;
    }

    if (S == 1) {
        #pragma unroll
        for (int qf = 0; qf < 2; ++qf) {
            float lr = lpart[qf];
            lr += __shfl_xor(lr, 16);
            lr += __shfl_xor(lr, 32);
            const float linv = 1.0f / lr;
            const int n = n0 + wvi * 32 + qf * 16 + c;
            #pragma unroll
            for (int nf = 0; nf < 4; ++nf) {
                float4 o4 = make_float4(of[qf][nf][0] * linv, of[qf][nf][1] * linv,
                                        of[qf][nf][2] * linv, of[qf][nf][3] * linv);
                *(float4*)(out + (((size_t)b * Nn + n) << 6) + nf * 16 + g * 4) = o4;
            }
        }
    } else {
        #pragma unroll
        for (int qf = 0; qf < 2; ++qf) {
            float lr = lpart[qf];
            lr += __shfl_xor(lr, 16);
            lr += __shfl_xor(lr, 32);
            const float linv = 1.0f / lr;
            const int n = n0 + wvi * 32 + qf * 16 + c;
            size_t robase = (((size_t)sp * Bn + b) * Nn + n) << 6;
            #pragma unroll
            for (int nf = 0; nf < 4; ++nf) {
                union { f16x4 v4; fp16x2 h2[2]; } u;
                u.h2[0] = __builtin_amdgcn_cvt_pkrtz(of[qf][nf][0] * linv, of[qf][nf][1] * linv);
                u.h2[1] = __builtin_amdgcn_cvt_pkrtz(of[qf][nf][2] * linv, of[qf][nf][3] * linv);
                *(f16x4*)(Opart + robase + nf * 16 + g * 4) = u.v4;
            }
            if (g == 0) {
                lw[((size_t)sp * Bn + b) * Nn + n] = lr * exp2f(m_run[qf]);
            }
        }
    }
}

// ---------------------------------------------------------------------------
// Kernel 4: combine with true weights (no max pass). 8 outputs per thread.
__global__ __launch_bounds__(256) void combine(
    const f16* __restrict__ Opart, const float* __restrict__ lw,
    float* __restrict__ out, int S)
{
    const int idx8 = blockIdx.x * 256 + threadIdx.x;
    const int w8 = idx8 & 7;
    const int n  = (idx8 >> 3) & (Nn - 1);
    const int b  = idx8 >> 15;
    float num[8];
    #pragma unroll
    for (int j = 0; j < 8; ++j) num[j] = 0.f;
    float den = 0.f;
    for (int s = 0; s < S; ++s) {
        float a = lw[((size_t)s * Bn + b) * Nn + n];
        f16x8 o8 = *(const f16x8*)(Opart + ((((size_t)s * Bn + b) * Nn + n) << 6) + w8 * 8);
        #pragma unroll
        for (int j = 0; j < 8; ++j) num[j] += a * (float)o8[j];
        den += a;
    }
    const float di = 1.0f / den;
    float* op = out + (((size_t)b * Nn + n) << 6) + w8 * 8;
    float4 lo = make_float4(num[0] * di, num[1] * di, num[2] * di, num[3] * di);
    float4 hi = make_float4(num[4] * di, num[5] * di, num[6] * di, num[7] * di);
    *(float4*)op = lo;
    *(float4*)(op + 4) = hi;
}

// ---------------------------------------------------------------------------
extern "C" void kernel_launch(void* const* d_in, const int* in_sizes, int n_in,
                              void* d_out, int out_size, void* d_ws, size_t ws_size,
                              hipStream_t stream)
{
    const float* v1 = (const float*)d_in[0];
    const float* v2 = (const float*)d_in[1];
    const float* wq = (const float*)d_in[2];
    const float* bq = (const float*)d_in[3];
    const float* wk = (const float*)d_in[4];
    const float* bk = (const float*)d_in[5];
    const float* wv = (const float*)d_in[6];
    const float* bv = (const float*)d_in[7];
    float* out = (float*)d_out;

    char* ws = (char*)d_ws;
    const size_t T = (size_t)TS * sizeof(f16);  // 2 MB per f16 tensor
    f16* Qh = (f16*)(ws + 0 * T);
    f16* Kh = (f16*)(ws + 1 * T);
    f16* Vh = (f16*)(ws + 2 * T);
    f16* Vt = (f16*)(ws + 3 * T);
    const size_t base = 4 * T;                       // 8 MB
    const size_t opartBytes = (size_t)TS * 2;        // 2 MB per split (f16)
    const size_t lwBytes    = (size_t)Bn * Nn * 4;   // 64 KB per split

    int S = 1;
    if      (ws_size >= base + 8 * (opartBytes + lwBytes)) S = 8;
    else if (ws_size >= base + 4 * (opartBytes + lwBytes)) S = 4;
    else if (ws_size >= base + 2 * (opartBytes + lwBytes)) S = 2;

    f16*   Opart = (f16*)(ws + base);
    float* lwp   = (float*)(ws + base + (size_t)S * opartBytes);

    qkv_conv<<<dim3(64, 4, 3), 512, 0, stream>>>(v1, v2, wq, bq, wk, bk, wv, bv,
                                                 Qh, Kh, Vh);
    vtrans<<<dim3(64, 4), 256, 0, stream>>>(Vh, Vt);
    attn<<<dim3(16, S, 4), 512, 0, stream>>>(Qh, Kh, Vt, out, Opart, lwp);
    if (S > 1) {
        combine<<<(Bn * Nn * Dd / 8) / 256, 256, 0, stream>>>(Opart, lwp, out, S);
    }
}

// Round 20
// 59.069 us; speedup vs baseline: 1.0703x; 1.0703x over previous
//
#include <hip/hip_runtime.h>

// B=4, C=64, H=64, W=64. Tokens N = C*H = 4096, feature dim D = W = 64.
// q = conv1x1(v1,wq,bq); k,v = conv1x1(v2,...); scores = q@k^T (no scale);
// softmax; out = attn@v. Output fp32, flat (B,C,H,W) == (B,N,D).
//
// R20: KVBLK=128 attn. One softmax pass per 128 keys (was 2) -> serial
// chain per key cut ~40%. qf=1 (16 q-rows/wave) keeps regs ~90 < 128
// budget at (512,4). Grid (32, S=4, 4) = 512 blocks = one round; combine
// traffic halved. Conv stays MFMA GEMM (R18); combine stays lw (R16).

#define Bn 4
#define Cc 64
#define HW 4096
#define Nn 4096
#define Dd 64
#define TS (Bn * Nn * Dd)   // elems per (B,N,D) tensor = 1048576
#define LOG2E 1.44269504088896340736f

typedef _Float16 f16;
typedef _Float16 f16x8 __attribute__((ext_vector_type(8)));
typedef _Float16 f16x4 __attribute__((ext_vector_type(4)));
typedef __fp16 fp16x2 __attribute__((ext_vector_type(2)));
typedef float f32x4 __attribute__((ext_vector_type(4)));

__device__ __forceinline__ int swz(int row, int col) {
    return row * 64 + (col ^ ((row & 7) << 3));
}

// Async global->LDS DMA, 16B per lane. LDS dest = uniform base + lane*16.
__device__ __forceinline__ void gl_lds16(const f16* g, f16* l) {
    __builtin_amdgcn_global_load_lds(
        (const __attribute__((address_space(1))) unsigned int*)g,
        (__attribute__((address_space(3))) unsigned int*)l, 16, 0, 0);
}

// ---------------------------------------------------------------------------
// Kernel 1: 1x1 conv as MFMA GEMM (verified R18). blockIdx.z: 0=Q,1=K,2=V.
__global__ __launch_bounds__(512) void qkv_conv(
    const float* __restrict__ v1, const float* __restrict__ v2,
    const float* __restrict__ wq, const float* __restrict__ bq,
    const float* __restrict__ wk, const float* __restrict__ bk,
    const float* __restrict__ wv, const float* __restrict__ bv,
    f16* __restrict__ Qh, f16* __restrict__ Kh, f16* __restrict__ Vh)
{
    __shared__ __align__(16) f16 wl[64 * 72];   // W[o][c], row stride 72
    __shared__ __align__(16) f16 Xt[64 * 72];   // X^T[dp][c], row stride 72
    __shared__ __align__(16) float bl[64];

    const int t    = threadIdx.x;
    const int lane = t & 63, wvi = t >> 6;
    const int g = lane >> 4, c = lane & 15;
    const int b   = blockIdx.y;
    const int blk = blockIdx.x;
    const int z   = blockIdx.z;          // 0=Q, 1=K, 2=V

    const float* w    = (z == 0) ? wq : (z == 1) ? wk : wv;
    const float* bias = (z == 0) ? bq : (z == 1) ? bk : bv;
    const float* x    = ((z == 0) ? v1 : v2) + (size_t)b * (Cc * HW) + blk * 64;
    f16* dst          = (z == 0) ? Qh : (z == 1) ? Kh : Vh;
    const float scale = (z == 0) ? LOG2E : 1.0f;

    for (int i = t; i < 4096; i += 512)
        wl[(i >> 6) * 72 + (i & 63)] = (f16)(w[i] * scale);
    if (t < 64) bl[t] = bias[t] * scale;
    {
        const int cch = t >> 3, dp0 = (t & 7) * 8;
        float4 x0 = *(const float4*)(x + (size_t)cch * HW + dp0);
        float4 x1 = *(const float4*)(x + (size_t)cch * HW + dp0 + 4);
        Xt[(dp0 + 0) * 72 + cch] = (f16)x0.x;
        Xt[(dp0 + 1) * 72 + cch] = (f16)x0.y;
        Xt[(dp0 + 2) * 72 + cch] = (f16)x0.z;
        Xt[(dp0 + 3) * 72 + cch] = (f16)x0.w;
        Xt[(dp0 + 4) * 72 + cch] = (f16)x1.x;
        Xt[(dp0 + 5) * 72 + cch] = (f16)x1.y;
        Xt[(dp0 + 6) * 72 + cch] = (f16)x1.z;
        Xt[(dp0 + 7) * 72 + cch] = (f16)x1.w;
    }
    __syncthreads();

    const int fn  = wvi & 3;        // dp block
    const int fo2 = (wvi >> 2) * 2; // first of 2 o-blocks

    f16x8 xb0 = *(const f16x8*)(Xt + (fn * 16 + c) * 72 + g * 8);
    f16x8 xb1 = *(const f16x8*)(Xt + (fn * 16 + c) * 72 + 32 + g * 8);

    #pragma unroll
    for (int fi = 0; fi < 2; ++fi) {
        const int fo = fo2 + fi;
        f16x8 wa0 = *(const f16x8*)(wl + (fo * 16 + c) * 72 + g * 8);
        f16x8 wa1 = *(const f16x8*)(wl + (fo * 16 + c) * 72 + 32 + g * 8);
        f32x4 acc = *(const f32x4*)(bl + fo * 16 + g * 4);   // bias init
        acc = __builtin_amdgcn_mfma_f32_16x16x32_f16(wa0, xb0, acc, 0, 0, 0);
        acc = __builtin_amdgcn_mfma_f32_16x16x32_f16(wa1, xb1, acc, 0, 0, 0);
        #pragma unroll
        for (int r = 0; r < 4; ++r) {
            const int o = fo * 16 + g * 4 + r;
            const int n = o * 64 + blk;
            dst[(size_t)b * (Nn * Dd) + (size_t)n * 64 + fn * 16 + c] = (f16)acc[r];
        }
    }
}

// ---------------------------------------------------------------------------
// Kernel 2: transpose V (B,N,D) -> Vt (B,D,N).
__global__ __launch_bounds__(256) void vtrans(const f16* __restrict__ Vh,
                                              f16* __restrict__ Vt)
{
    __shared__ f16 tile[64][72];
    const int t  = threadIdx.x;
    const int n0 = blockIdx.x * 64;
    const int b  = blockIdx.y;
    for (int i = t; i < 4096; i += 256) {
        int r = i >> 6, c = i & 63;
        tile[r][c] = Vh[(size_t)b * (Nn * Dd) + (size_t)(n0 + r) * 64 + c];
    }
    __syncthreads();
    for (int i = t; i < 4096; i += 256) {
        int w = i >> 6, n = i & 63;
        Vt[(size_t)b * (Dd * Nn) + (size_t)w * Nn + n0 + n] = tile[n][w];
    }
}

// ---------------------------------------------------------------------------
// Kernel 3: flash attention, split-K, KVBLK=128 (one softmax per 128 keys).
// 512 threads = 8 waves x 16 q-rows (block = 128 rows). grid (32, S, 4);
// S=4 -> 512 blocks = one resident round at (512,4). LDS 64KB: dbuf x
// 2 sub-tiles of 64 keys each.
// QK^T: S^T = mfma_16x16x32(A=K, B=Q^T): lane (g,c) holds
//   S[key = fm*16+g*4+r][q=c] in accS[fm][r], fm = 0..7 (128 keys).
// PV:  O^T = mfma_16x16x16(A=V^T-frag, B=pk_f16(accS)): lane holds
//   O[q=c][d = nf*16+g*4+r].
__global__ __launch_bounds__(512, 4) void attn(
    const f16* __restrict__ Qhg, const f16* __restrict__ Khg,
    const f16* __restrict__ Vtg,
    float* __restrict__ out, f16* __restrict__ Opart, float* __restrict__ lw)
{
    __shared__ __align__(16) f16 KT[2][2][4096];  // [buf][sub][key][d] swz
    __shared__ __align__(16) f16 VT[2][2][4096];  // [buf][sub][d][key] swz

    const int t    = threadIdx.x;
    const int lane = t & 63, wvi = t >> 6;      // 8 waves
    const int g = lane >> 4, c = lane & 15;
    const int b  = blockIdx.z;
    const int sp = blockIdx.y;
    const int S  = gridDim.y;
    const int n0 = blockIdx.x * 128;
    const int keysPerSplit = Nn / S;
    const int nTiles = keysPerSplit / 128;      // 128-key tiles
    const int kbase = sp * keysPerSplit;

    const int srow = t >> 3;                      // 0..63
    const int gc   = ((t & 7) ^ (srow & 7)) * 8;  // pre-swizzled global col
    const int ldsoff = (wvi * 8) * 64;            // wave-uniform dest offset

    const f16* Kb = Khg + (size_t)b * (Nn * Dd);
    const f16* Vb = Vtg + (size_t)b * (Dd * Nn);

    // Hoist Q B-fragment (single f16, pre-scaled by log2e). q-row = c.
    f16x8 qbh[2];
    {
        const int qrow = n0 + wvi * 16 + c;
        const f16* qhp = Qhg + ((size_t)b * Nn + qrow) * 64;
        #pragma unroll
        for (int ks = 0; ks < 2; ++ks)
            qbh[ks] = *(const f16x8*)(qhp + ks * 32 + g * 8);
    }

    float m_run = -1e30f, lpart = 0.f;
    f32x4 of[4];   // of[nf][r] = O[q=c][d = nf*16 + g*4 + r]
    #pragma unroll
    for (int nf = 0; nf < 4; ++nf)
        #pragma unroll
        for (int r = 0; r < 4; ++r) of[nf][r] = 0.f;

    // Prologue: DMA tile 0 (both 64-key subs) into buffer 0.
    #pragma unroll
    for (int sub = 0; sub < 2; ++sub) {
        const int k0 = kbase + sub * 64;
        gl_lds16(Kb + (size_t)(k0 + srow) * 64 + gc, &KT[0][sub][ldsoff]);
        gl_lds16(Vb + (size_t)srow * Nn + k0 + gc, &VT[0][sub][ldsoff]);
    }
    __syncthreads();
    int cur = 0;

    for (int kt = 0; kt < nTiles; ++kt) {
        // Issue next tile's DMA into the free buffer (lands under compute).
        if (kt + 1 < nTiles) {
            const int kp = kbase + (kt + 1) * 128;
            #pragma unroll
            for (int sub = 0; sub < 2; ++sub) {
                const int k0 = kp + sub * 64;
                gl_lds16(Kb + (size_t)(k0 + srow) * 64 + gc, &KT[cur ^ 1][sub][ldsoff]);
                gl_lds16(Vb + (size_t)srow * Nn + k0 + gc, &VT[cur ^ 1][sub][ldsoff]);
            }
        }

        // ---- QK^T over 128 keys (fm = 0..7; sub = fm>>2) ----
        f32x4 accS[8];
        #pragma unroll
        for (int fm = 0; fm < 8; ++fm)
            #pragma unroll
            for (int r = 0; r < 4; ++r) accS[fm][r] = 0.f;
        #pragma unroll
        for (int fm = 0; fm < 8; ++fm) {
            const f16* KTc = KT[cur][fm >> 2];
            const int key = (fm & 3) * 16 + c;
            f16x8 kh0 = *(const f16x8*)(KTc + swz(key, g * 8));
            f16x8 kh1 = *(const f16x8*)(KTc + swz(key, 32 + g * 8));
            accS[fm] = __builtin_amdgcn_mfma_f32_16x16x32_f16(kh0, qbh[0], accS[fm], 0, 0, 0);
            accS[fm] = __builtin_amdgcn_mfma_f32_16x16x32_f16(kh1, qbh[1], accS[fm], 0, 0, 0);
        }

        // ---- ONE softmax pass for all 128 keys (defer-max THR=8, log2) ----
        f16x4 pb[8];
        {
            float mx[8];
            #pragma unroll
            for (int fm = 0; fm < 8; ++fm)
                mx[fm] = fmaxf(fmaxf(accS[fm][0], accS[fm][1]),
                               fmaxf(accS[fm][2], accS[fm][3]));
            float t0 = fmaxf(fmaxf(mx[0], mx[1]), fmaxf(mx[2], mx[3]));
            float t1 = fmaxf(fmaxf(mx[4], mx[5]), fmaxf(mx[6], mx[7]));
            float tmax = fmaxf(t0, t1);
            tmax = fmaxf(tmax, __shfl_xor(tmax, 16));
            tmax = fmaxf(tmax, __shfl_xor(tmax, 32));
            if (!__all(tmax <= m_run + 8.f)) {
                const float mnew = fmaxf(m_run, tmax);
                const float corr = exp2f(m_run - mnew);
                lpart *= corr;
                #pragma unroll
                for (int nf = 0; nf < 4; ++nf)
                    #pragma unroll
                    for (int r = 0; r < 4; ++r) of[nf][r] *= corr;  // lane-local
                m_run = mnew;
            }
            float s0 = 0.f, s1 = 0.f;
            #pragma unroll
            for (int fm = 0; fm < 8; ++fm) {
                float p0 = exp2f(accS[fm][0] - m_run);
                float p1 = exp2f(accS[fm][1] - m_run);
                float p2 = exp2f(accS[fm][2] - m_run);
                float p3 = exp2f(accS[fm][3] - m_run);
                if (fm < 4) s0 += (p0 + p1) + (p2 + p3);
                else        s1 += (p0 + p1) + (p2 + p3);
                union { f16x4 v4; fp16x2 h2[2]; } u;
                u.h2[0] = __builtin_amdgcn_cvt_pkrtz(p0, p1);
                u.h2[1] = __builtin_amdgcn_cvt_pkrtz(p2, p3);
                pb[fm] = u.v4;
            }
            lpart += s0 + s1;   // per-lane; reduce at epilogue
        }

        // ---- PV (16x16x16) over 128 keys ----
        #pragma unroll
        for (int nf = 0; nf < 4; ++nf) {
            #pragma unroll
            for (int fm = 0; fm < 8; ++fm) {
                const f16* VTc = VT[cur][fm >> 2];
                f16x4 va = *(const f16x4*)(VTc + swz(nf * 16 + c, (fm & 3) * 16 + g * 4));
                of[nf] = __builtin_amdgcn_mfma_f32_16x16x16f16(va, pb[fm], of[nf], 0, 0, 0);
            }
        }

        // One barrier per 128-key tile: drains DMA (vmcnt) + LDS reads.
        __syncthreads();
        cur ^= 1;
    }

    if (S == 1) {
        float lr = lpart;
        lr += __shfl_xor(lr, 16);
        lr += __shfl_xor(lr, 32);
        const float linv = 1.0f / lr;   // lane-local (q = c)
        const int n = n0 + wvi * 16 + c;
        #pragma unroll
        for (int nf = 0; nf < 4; ++nf) {
            float4 o4 = make_float4(of[nf][0] * linv, of[nf][1] * linv,
                                    of[nf][2] * linv, of[nf][3] * linv);
            *(float4*)(out + (((size_t)b * Nn + n) << 6) + nf * 16 + g * 4) = o4;
        }
    } else {
        // Normalized f16 partials (O/l) + true weight lw = l * 2^m.
        float lr = lpart;
        lr += __shfl_xor(lr, 16);
        lr += __shfl_xor(lr, 32);
        const float linv = 1.0f / lr;
        const int n = n0 + wvi * 16 + c;
        size_t robase = (((size_t)sp * Bn + b) * Nn + n) << 6;
        #pragma unroll
        for (int nf = 0; nf < 4; ++nf) {
            union { f16x4 v4; fp16x2 h2[2]; } u;
            u.h2[0] = __builtin_amdgcn_cvt_pkrtz(of[nf][0] * linv, of[nf][1] * linv);
            u.h2[1] = __builtin_amdgcn_cvt_pkrtz(of[nf][2] * linv, of[nf][3] * linv);
            *(f16x4*)(Opart + robase + nf * 16 + g * 4) = u.v4;
        }
        if (g == 0) {
            lw[((size_t)sp * Bn + b) * Nn + n] = lr * exp2f(m_run);
        }
    }
}

// ---------------------------------------------------------------------------
// Kernel 4: combine with true weights (no max pass). 8 outputs per thread.
__global__ __launch_bounds__(256) void combine(
    const f16* __restrict__ Opart, const float* __restrict__ lw,
    float* __restrict__ out, int S)
{
    const int idx8 = blockIdx.x * 256 + threadIdx.x;
    const int w8 = idx8 & 7;
    const int n  = (idx8 >> 3) & (Nn - 1);
    const int b  = idx8 >> 15;
    float num[8];
    #pragma unroll
    for (int j = 0; j < 8; ++j) num[j] = 0.f;
    float den = 0.f;
    for (int s = 0; s < S; ++s) {
        float a = lw[((size_t)s * Bn + b) * Nn + n];
        f16x8 o8 = *(const f16x8*)(Opart + ((((size_t)s * Bn + b) * Nn + n) << 6) + w8 * 8);
        #pragma unroll
        for (int j = 0; j < 8; ++j) num[j] += a * (float)o8[j];
        den += a;
    }
    const float di = 1.0f / den;
    float* op = out + (((size_t)b * Nn + n) << 6) + w8 * 8;
    float4 lo = make_float4(num[0] * di, num[1] * di, num[2] * di, num[3] * di);
    float4 hi = make_float4(num[4] * di, num[5] * di, num[6] * di, num[7] * di);
    *(float4*)op = lo;
    *(float4*)(op + 4) = hi;
}

// ---------------------------------------------------------------------------
extern "C" void kernel_launch(void* const* d_in, const int* in_sizes, int n_in,
                              void* d_out, int out_size, void* d_ws, size_t ws_size,
                              hipStream_t stream)
{
    const float* v1 = (const float*)d_in[0];
    const float* v2 = (const float*)d_in[1];
    const float* wq = (const float*)d_in[2];
    const float* bq = (const float*)d_in[3];
    const float* wk = (const float*)d_in[4];
    const float* bk = (const float*)d_in[5];
    const float* wv = (const float*)d_in[6];
    const float* bv = (const float*)d_in[7];
    float* out = (float*)d_out;

    char* ws = (char*)d_ws;
    const size_t T = (size_t)TS * sizeof(f16);  // 2 MB per f16 tensor
    f16* Qh = (f16*)(ws + 0 * T);
    f16* Kh = (f16*)(ws + 1 * T);
    f16* Vh = (f16*)(ws + 2 * T);
    f16* Vt = (f16*)(ws + 3 * T);
    const size_t base = 4 * T;                       // 8 MB
    const size_t opartBytes = (size_t)TS * 2;        // 2 MB per split (f16)
    const size_t lwBytes    = (size_t)Bn * Nn * 4;   // 64 KB per split

    int S = 1;
    if      (ws_size >= base + 4 * (opartBytes + lwBytes)) S = 4;
    else if (ws_size >= base + 2 * (opartBytes + lwBytes)) S = 2;

    f16*   Opart = (f16*)(ws + base);
    float* lwp   = (float*)(ws + base + (size_t)S * opartBytes);

    qkv_conv<<<dim3(64, 4, 3), 512, 0, stream>>>(v1, v2, wq, bq, wk, bk, wv, bv,
                                                 Qh, Kh, Vh);
    vtrans<<<dim3(64, 4), 256, 0, stream>>>(Vh, Vt);
    attn<<<dim3(32, S, 4), 512, 0, stream>>>(Qh, Kh, Vt, out, Opart, lwp);
    if (S > 1) {
        combine<<<(Bn * Nn * Dd / 8) / 256, 256, 0, stream>>>(Opart, lwp, out, S);
    }
}